// Round 19
// baseline (420.337 us; speedup 1.0000x reference)
//
#include <hip/hip_runtime.h>

#define NNODES 50000
#define NEDGES 800000
#define NG 50
#define PI_OVER_CUT 0.31415926535897931f
#define LN2 0.69314718055994531f

static_assert(NEDGES % 16 == 0, "edge tiling assumes E % 16 == 0");
static_assert((NG & 1) == 0, "pair loads assume NG even");
#define NTILES (NEDGES / 16)
static_assert(NTILES % 8 == 0, "XCD partition assumes NTILES % 8 == 0");
#define SCAN_N 50176            // 196 * 256 >= NNODES
#define SCAN_BLK 196

typedef float f32x4 __attribute__((ext_vector_type(4)));
typedef float f32x2 __attribute__((ext_vector_type(2)));
typedef float f32x4u __attribute__((ext_vector_type(4), aligned(4)));
typedef short s16x8 __attribute__((ext_vector_type(8)));

// packed f32x2 -> bf16x2 (RNE), single instruction on gfx950
static __device__ __forceinline__ unsigned cvt_pk(float lo, float hi) {
  unsigned r;
  asm("v_cvt_pk_bf16_f32 %0, %1, %2" : "=v"(r) : "v"(lo), "v"(hi));
  return r;
}

static __device__ __forceinline__ short f2bf(float f) {
  union { float f; unsigned u; } v; v.f = f;
  return (short)((v.u + 0x7fffu + ((v.u >> 16) & 1u)) >> 16);  // RNE
}

static __device__ __forceinline__ float bf2f(unsigned short u) {
  union { unsigned u; float f; } v; v.u = (unsigned)u << 16;
  return v.f;
}

// softplus(x) - ln2, numerically stable (fallback-kernel use)
static __device__ __forceinline__ float sp_shift(float x) {
  return fmaxf(x, 0.f) + __logf(1.f + __expf(-fabsf(x))) - LN2;
}

// w such that softplus(x) = w * ln2. ~5 HW ops.
// Overflow-safe for x < ~80 (|acc| bounded ~55 here); large-negative -> 0 exactly.
static __device__ __forceinline__ float sp_w(float x) {
  return __log2f(1.f + __expf(x));
}

#define MFMA16(A, B, C) __builtin_amdgcn_mfma_f32_16x16x32_bf16((A), (B), (C), 0, 0, 0)

// h1bT layout: [node][lr<16][t<8] bf16 (element (lr,t) = h1[node][t*16+lr]).
// 256B per node. Edge-kernel gather of one lane's 8 values = one 16B load.

// ------- MFMA lin1: h1bT = bf16(X @ W^T) (transposed frag layout);
//         also zeroes this block's agg rows --------------------------------
__global__ __launch_bounds__(256) void lin1_mfma(const float* __restrict__ X,
                                                 const float* __restrict__ W,
                                                 unsigned short* __restrict__ Y2, // h1bT
                                                 float* __restrict__ aggz) {
  __shared__ __align__(16) short sB[16384];  // W frags: [s<4][t<8][lane][8]
  const int tid = threadIdx.x;
  if (aggz) {
    const size_t b0 = (size_t)blockIdx.x * 64 * 128;
    const size_t lim = (size_t)NNODES * 128;
    for (int i = tid; i < 64 * 32; i += 256) {
      size_t off = b0 + (size_t)i * 4;
      if (off < lim) *(f32x4*)(aggz + off) = f32x4{0.f, 0.f, 0.f, 0.f};
    }
  }
  for (int i = tid; i < 8192; i += 256) {    // i indexes bf16-pairs
    int p = i & 3, l = (i >> 2) & 63, t = (i >> 8) & 7, s = i >> 11;
    int k = s * 32 + (l >> 4) * 8 + p * 2;
    int f = t * 16 + (l & 15);
    f32x2 v = *(const f32x2*)(W + f * 128 + k);
    ((unsigned*)sB)[i] = cvt_pk(v.x, v.y);
  }
  __syncthreads();
  const int lane = tid & 63, wave = tid >> 6, lrow = lane & 15, lk = lane >> 4;
  const s16x8* B = (const s16x8*)sB;
  const int rowA = blockIdx.x * 64 + wave * 16 + lrow;
  s16x8 a[4];
#pragma unroll
  for (int s = 0; s < 4; ++s) {
    unsigned* ap = (unsigned*)&a[s];
    f32x4 v0 = {}, v1 = {};
    if (rowA < NNODES) {
      const float* xr = X + (size_t)rowA * 128 + s * 32 + lk * 8;
      v0 = *(const f32x4*)xr;
      v1 = *(const f32x4*)(xr + 4);
    }
    ap[0] = cvt_pk(v0.x, v0.y); ap[1] = cvt_pk(v0.z, v0.w);
    ap[2] = cvt_pk(v1.x, v1.y); ap[3] = cvt_pk(v1.z, v1.w);
  }
  f32x4 acc[8] = {};
#pragma unroll
  for (int s = 0; s < 4; ++s)
#pragma unroll
    for (int t = 0; t < 8; ++t)
      acc[t] = MFMA16(a[s], B[(s * 8 + t) * 64 + lane], acc[t]);
  const int rowD = blockIdx.x * 64 + wave * 16 + lk * 4;
#pragma unroll
  for (int r = 0; r < 4; ++r) {
    int node = rowD + r;
    if (node < NNODES) {
      uint4 q;
      q.x = cvt_pk(acc[0][r], acc[1][r]);
      q.y = cvt_pk(acc[2][r], acc[3][r]);
      q.z = cvt_pk(acc[4][r], acc[5][r]);
      q.w = cvt_pk(acc[6][r], acc[7][r]);
      *(uint4*)(Y2 + (size_t)node * 128 + lrow * 8) = q;
    }
  }
}

// ---------------- MFMA lin2: OUT = (bf2f(h1bT) + AG) @ W^T + b ---------------
// AG may alias OUT (in-place): each wave reads/writes only its own 16 rows.
__global__ __launch_bounds__(256) void lin2_mfma(const unsigned short* __restrict__ H1bT,
                                                 const float* AG,
                                                 const float* __restrict__ W,
                                                 const float* __restrict__ Bias,
                                                 float* OUT) {
  __shared__ __align__(16) short sB[16384];
  const int tid = threadIdx.x;
  for (int i = tid; i < 8192; i += 256) {
    int p = i & 3, l = (i >> 2) & 63, t = (i >> 8) & 7, s = i >> 11;
    int k = s * 32 + (l >> 4) * 8 + p * 2;
    int f = t * 16 + (l & 15);
    f32x2 v = *(const f32x2*)(W + f * 128 + k);
    ((unsigned*)sB)[i] = cvt_pk(v.x, v.y);
  }
  __syncthreads();
  const int lane = tid & 63, wave = tid >> 6, lrow = lane & 15, lk = lane >> 4;
  const s16x8* B = (const s16x8*)sB;
  const int rowA = blockIdx.x * 64 + wave * 16 + lrow;
  s16x8 a[4];
#pragma unroll
  for (int s = 0; s < 4; ++s) {
    unsigned* ap = (unsigned*)&a[s];
    float w[8] = {};
    if (rowA < NNODES) {
      const float* gr = AG + (size_t)rowA * 128 + s * 32 + lk * 8;
      f32x4 g0 = *(const f32x4*)gr;
      f32x4 g1 = *(const f32x4*)(gr + 4);
#pragma unroll
      for (int j = 0; j < 8; ++j) {
        int c = s * 32 + lk * 8 + j;   // original column
        float hv = bf2f(H1bT[(size_t)rowA * 128 + (c & 15) * 8 + (c >> 4)]);
        w[j] = hv + (j < 4 ? g0[j] : g1[j - 4]);
      }
    }
    ap[0] = cvt_pk(w[0], w[1]); ap[1] = cvt_pk(w[2], w[3]);
    ap[2] = cvt_pk(w[4], w[5]); ap[3] = cvt_pk(w[6], w[7]);
  }
  f32x4 acc[8] = {};
#pragma unroll
  for (int s = 0; s < 4; ++s)
#pragma unroll
    for (int t = 0; t < 8; ++t)
      acc[t] = MFMA16(a[s], B[(s * 8 + t) * 64 + lane], acc[t]);
  const int rowD = blockIdx.x * 64 + wave * 16 + lk * 4;
#pragma unroll
  for (int t = 0; t < 8; ++t) {
    float bb = Bias[t * 16 + lrow];
#pragma unroll
    for (int r = 0; r < 4; ++r)
      if (rowD + r < NNODES)
        OUT[(size_t)(rowD + r) * 128 + t * 16 + lrow] = acc[t][r] + bb;
  }
}

// ---------------- sort machinery ---------------------------------------------
__global__ void k_hist(const int* __restrict__ ei, int* __restrict__ cnt) {
  int e = blockIdx.x * 256 + threadIdx.x;
  if (e < NEDGES) atomicAdd(&cnt[ei[e]], 1);
}

__global__ __launch_bounds__(256) void k_scanA(int* __restrict__ cnt,
                                               int* __restrict__ bsum) {
  __shared__ int sh[256];
  const int t = threadIdx.x;
  const int i = blockIdx.x * 256 + t;
  int v = cnt[i];
  sh[t] = v;
  __syncthreads();
  for (int off = 1; off < 256; off <<= 1) {
    int u = (t >= off) ? sh[t - off] : 0;
    __syncthreads();
    sh[t] += u;
    __syncthreads();
  }
  cnt[i] = sh[t] - v;
  if (t == 255) bsum[blockIdx.x] = sh[255];
}

__global__ __launch_bounds__(256) void k_scanB(int* __restrict__ bsum) {
  __shared__ int sh[256];
  const int t = threadIdx.x;
  int v = (t < SCAN_BLK) ? bsum[t] : 0;
  sh[t] = v;
  __syncthreads();
  for (int off = 1; off < 256; off <<= 1) {
    int u = (t >= off) ? sh[t - off] : 0;
    __syncthreads();
    sh[t] += u;
    __syncthreads();
  }
  if (t < SCAN_BLK) bsum[t] = sh[t] - v;
}

__global__ __launch_bounds__(256) void k_scanC(int* __restrict__ cnt,
                                               const int* __restrict__ bsum) {
  int i = blockIdx.x * 256 + threadIdx.x;
  cnt[i] += bsum[blockIdx.x];
}

// ---- prepass: meta only (dst,src,cw,eid) scattered to sorted position -------
__global__ void k_prepM(const int* __restrict__ ei, const float* __restrict__ ew,
                        int* __restrict__ cursor, int4* __restrict__ meta) {
  int e = blockIdx.x * 256 + threadIdx.x;
  if (e >= NEDGES) return;
  int d = ei[e], s = ei[NEDGES + e];
  float c = 0.5f * (__cosf(ew[e] * PI_OVER_CUT) + 1.f);
  int pos = atomicAdd(&cursor[d], 1);
  meta[pos] = make_int4(d, s, __float_as_int(c), e);
}

// ---------------- K2: fused stage1+2, dst-sorted, meta-fed, 3-deep pipeline --
// LOADSET issues meta -> attr + h1bT gathers (two COMPUTESETs of latency slack).
#define LOADSET_M(S, TL)                                                       \
  {                                                                            \
    const int base_ = (TL) * 16;                                               \
    const int4* mp_ = meta + base_ + lk * 4;                                   \
    int4 m0_ = mp_[0], m1_ = mp_[1], m2_ = mp_[2], m3_ = mp_[3];               \
    dst_##S[0] = m0_.x; dst_##S[1] = m1_.x; dst_##S[2] = m2_.x; dst_##S[3] = m3_.x; \
    cw_##S[0] = __int_as_float(m0_.z); cw_##S[1] = __int_as_float(m1_.z);      \
    cw_##S[2] = __int_as_float(m2_.z); cw_##S[3] = __int_as_float(m3_.z);      \
    hv8_##S[0] = *(const s16x8*)(h1bT + (size_t)m0_.y * 128 + lrow * 8);       \
    hv8_##S[1] = *(const s16x8*)(h1bT + (size_t)m1_.y * 128 + lrow * 8);       \
    hv8_##S[2] = *(const s16x8*)(h1bT + (size_t)m2_.y * 128 + lrow * 8);       \
    hv8_##S[3] = *(const s16x8*)(h1bT + (size_t)m3_.y * 128 + lrow * 8);       \
    const int ser_ = meta[base_ + lrow].w;                                     \
    const float* ar_ = attr + (size_t)ser_ * NG;                               \
    unsigned* a0_ = (unsigned*)&av0_##S;                                       \
    unsigned* a1_ = (unsigned*)&av1_##S;                                       \
    if (ser_ < NEDGES - 1) {  /* fast: unmasked (pad lanes hit B=0) */         \
      f32x4u p0 = *(const f32x4u*)(ar_ + lk * 8);                              \
      f32x4u p1 = *(const f32x4u*)(ar_ + lk * 8 + 4);                          \
      f32x4u p2 = *(const f32x4u*)(ar_ + 32 + lk * 8);                         \
      f32x4u p3 = *(const f32x4u*)(ar_ + 32 + lk * 8 + 4);                     \
      a0_[0] = cvt_pk(p0.x, p0.y); a0_[1] = cvt_pk(p0.z, p0.w);                \
      a0_[2] = cvt_pk(p1.x, p1.y); a0_[3] = cvt_pk(p1.z, p1.w);                \
      a1_[0] = cvt_pk(p2.x, p2.y); a1_[1] = cvt_pk(p2.z, p2.w);                \
      a1_[2] = cvt_pk(p3.x, p3.y); a1_[3] = cvt_pk(p3.z, p3.w);                \
    } else {                                                                   \
      _Pragma("unroll") for (int jj = 0; jj < 4; ++jj) {                       \
        f32x2 v = *(const f32x2*)(ar_ + lk * 8 + jj * 2);                      \
        a0_[jj] = cvt_pk(v.x, v.y);                                            \
      }                                                                        \
      _Pragma("unroll") for (int jj = 0; jj < 4; ++jj) {                       \
        int k_ = 32 + lk * 8 + jj * 2;                                         \
        f32x2 v = {0.f, 0.f};                                                  \
        if (k_ < NG) v = *(const f32x2*)(ar_ + k_);                            \
        a1_[jj] = cvt_pk(v.x, v.y);                                            \
      }                                                                        \
    }                                                                          \
  }

#define COMPUTESET_M(S)                                                        \
  {                                                                            \
    f32x4 acc[8] = {};                                                         \
    _Pragma("unroll") for (int t = 0; t < 8; ++t)                              \
      acc[t] = MFMA16(av0_##S, B1r[t], acc[t]);                                \
    _Pragma("unroll") for (int t = 0; t < 8; ++t)                              \
      acc[t] = MFMA16(av1_##S, B1r[8 + t], acc[t]);                            \
    _Pragma("unroll") for (int t = 0; t < 8; ++t) {                            \
      int f = t * 16 + lrow;                                                   \
      float bb = sb1[f];                                                       \
      float w0 = sp_w(acc[t][0] + bb);                                         \
      float w1 = sp_w(acc[t][1] + bb);                                         \
      float w2 = sp_w(acc[t][2] + bb);                                         \
      float w3 = sp_w(acc[t][3] + bb);                                         \
      float v0 = __builtin_fmaf(w0, LN2, -LN2);                                \
      float v1 = __builtin_fmaf(w1, LN2, -LN2);                                \
      float v2 = __builtin_fmaf(w2, LN2, -LN2);                                \
      float v3 = __builtin_fmaf(w3, LN2, -LN2);                                \
      unsigned p01 = cvt_pk(v0, v1), p23 = cvt_pk(v2, v3);                     \
      const int row0_ = lk * 4;                                                \
      int a0 = ((row0_ + 0) * 256 + f * 2) ^ (((row0_ + 0) & 7) << 4);         \
      int a1 = ((row0_ + 1) * 256 + f * 2) ^ (((row0_ + 1) & 7) << 4);         \
      int a2 = ((row0_ + 2) * 256 + f * 2) ^ (((row0_ + 2) & 7) << 4);         \
      int a3 = ((row0_ + 3) * 256 + f * 2) ^ (((row0_ + 3) & 7) << 4);         \
      *(short*)(sXw + a0) = (short)p01;                                        \
      *(short*)(sXw + a1) = (short)(p01 >> 16);                                \
      *(short*)(sXw + a2) = (short)p23;                                        \
      *(short*)(sXw + a3) = (short)(p23 >> 16);                                \
    }                                                                          \
    f32x4 acc2[8] = {};                                                        \
    _Pragma("unroll") for (int s = 0; s < 4; ++s) {                            \
      int ab = (lrow * 256 + s * 64 + lk * 16) ^ ((lrow & 7) << 4);            \
      s16x8 av = *(const s16x8*)(sXw + ab);                                    \
      _Pragma("unroll") for (int t = 0; t < 8; ++t)                            \
        acc2[t] = MFMA16(av, B2[(s * 8 + t) * 64 + lane], acc2[t]);            \
    }                                                                          \
    const float lc0 = cw_##S[0] * LN2, lc1 = cw_##S[1] * LN2;                  \
    const float lc2 = cw_##S[2] * LN2, lc3 = cw_##S[3] * LN2;                  \
    const int d0 = dst_##S[0], d3 = dst_##S[3];                                \
    const bool b1f = dst_##S[1] != d0, b2f = dst_##S[2] != dst_##S[1],         \
               b3f = d3 != dst_##S[2];                                         \
    const bool allsame = !(b1f | b2f | b3f);                                   \
    const int next_head = __shfl(d0, (lane + 16) & 63);                        \
    const bool tor = (lk < 3) && (next_head == d3);                            \
    const int td0 = __shfl(d3, lrow);                                          \
    const int td1 = __shfl(d3, lrow + 16);                                     \
    const int td2 = __shfl(d3, lrow + 32);                                     \
    const bool m0 = (lk >= 1) && (td0 == d0);                                  \
    const bool m1 = (lk >= 2) && (td1 == d0);                                  \
    const bool m2 = (lk >= 3) && (td2 == d0);                                  \
    const bool emit_head = !(allsame && tor);                                  \
    const bool emit_tail = (!allsame) && !tor;                                 \
    const bool mid1 = b1f && b2f, mid2 = b2f && b3f,                           \
               mid12 = b1f && (!b2f) && b3f;                                   \
    _Pragma("unroll") for (int t = 0; t < 8; ++t) {                            \
      int f = t * 16 + lrow;                                                   \
      float bb = sb2[f];                                                       \
      float w0 = sp_w(acc2[t][0] + bb);                                        \
      float w1 = sp_w(acc2[t][1] + bb);                                        \
      float w2 = sp_w(acc2[t][2] + bb);                                        \
      float w3 = sp_w(acc2[t][3] + bb);                                        \
      float v0 = __builtin_fmaf(w0, lc0, -lc0) * bf2f((unsigned short)hv8_##S[0][t]); \
      float v1 = __builtin_fmaf(w1, lc1, -lc1) * bf2f((unsigned short)hv8_##S[1][t]); \
      float v2 = __builtin_fmaf(w2, lc2, -lc2) * bf2f((unsigned short)hv8_##S[2][t]); \
      float v3 = __builtin_fmaf(w3, lc3, -lc3) * bf2f((unsigned short)hv8_##S[3][t]); \
      float head_sum = v0 + (b1f ? 0.f : v1 + (b2f ? 0.f : v2 + (b3f ? 0.f : v3))); \
      float tail_sum = v3 + (b3f ? 0.f : v2 + (b2f ? 0.f : v1 + (b1f ? 0.f : v0))); \
      float ts0 = __shfl(tail_sum, lrow);                                      \
      float ts1 = __shfl(tail_sum, lrow + 16);                                 \
      float ts2 = __shfl(tail_sum, lrow + 32);                                 \
      float carry = (m0 ? ts0 : 0.f) + (m1 ? ts1 : 0.f) + (m2 ? ts2 : 0.f);    \
      if (emit_head) atomicAdd(&agg[(size_t)d0 * 128 + f], head_sum + carry);  \
      if (emit_tail) atomicAdd(&agg[(size_t)d3 * 128 + f], tail_sum);          \
      if (mid1) atomicAdd(&agg[(size_t)dst_##S[1] * 128 + f], v1);             \
      if (mid2) atomicAdd(&agg[(size_t)dst_##S[2] * 128 + f], v2);             \
      if (mid12) atomicAdd(&agg[(size_t)dst_##S[1] * 128 + f], v1 + v2);       \
    }                                                                          \
  }

// XCD-aware partition: blocks presumed round-robin over 8 XCDs (bid & 7).
__global__ __launch_bounds__(256, 2) void cfconv_edge_m(
    const int4* __restrict__ meta, const float* __restrict__ attr,
    const float* __restrict__ w1, const float* __restrict__ b1,
    const float* __restrict__ w2, const float* __restrict__ b2,
    const unsigned short* __restrict__ h1bT, float* __restrict__ agg) {
  __shared__ __align__(16) short sB2[16384];   // W2^T frags: [s<4][t<8][lane][8]
  __shared__ __align__(16) short sX[4][2048];  // per-wave X tile [16][128] bf16, swizzled
  __shared__ float sb1[128], sb2[128];
  const int tid = threadIdx.x;
  if (tid < 128) { sb1[tid] = b1[tid]; sb2[tid] = b2[tid]; }
  for (int i = tid; i < 8192; i += 256) {
    int p = i & 3, l = (i >> 2) & 63, t = (i >> 8) & 7, s = i >> 11;
    int k = s * 32 + (l >> 4) * 8 + p * 2;
    int f = t * 16 + (l & 15);
    f32x2 v = *(const f32x2*)(w2 + f * 128 + k);
    ((unsigned*)sB2)[i] = cvt_pk(v.x, v.y);
  }
  __syncthreads();
  const int lane = tid & 63;
  const int wave = tid >> 6;
  const int lrow = lane & 15;
  const int lk = lane >> 4;
  // B1 frags -> registers (16 frags x 4 VGPR), built once per wave
  s16x8 B1r[16];
  {
    unsigned* bp = (unsigned*)B1r;
#pragma unroll
    for (int s = 0; s < 2; ++s)
#pragma unroll
      for (int t = 0; t < 8; ++t) {
        const float* wrow = w1 + (t * 16 + lrow) * NG;
#pragma unroll
        for (int p = 0; p < 4; ++p) {
          int k = s * 32 + lk * 8 + p * 2;
          f32x2 v = {0.f, 0.f};
          if (k < NG) v = *(const f32x2*)(wrow + k);
          bp[(s * 8 + t) * 4 + p] = cvt_pk(v.x, v.y);
        }
      }
  }
  const s16x8* B2 = (const s16x8*)sB2;
  char* sXw = (char*)sX[wave];

  // XCD partition of tile space
  const int xcd  = blockIdx.x & 7;
  const int lb   = blockIdx.x >> 3;
  const int tpx  = NTILES / 8;
  const int tend = (xcd + 1) * tpx;
  const int ls   = (gridDim.x >> 3) * 4;
  const int gw0  = xcd * tpx + lb * 4 + wave;

  s16x8 av0_A, av1_A, av0_B, av1_B, av0_C, av1_C;
  s16x8 hv8_A[4], hv8_B[4], hv8_C[4];
  int dst_A[4], dst_B[4], dst_C[4];
  float cw_A[4], cw_B[4], cw_C[4];

  int tl = gw0;
  if (tl < tend) LOADSET_M(A, tl);
  if (tl + ls < tend) LOADSET_M(B, tl + ls);
  while (tl < tend) {
    { int n = tl + 2 * ls; if (n < tend) LOADSET_M(C, n); }
    COMPUTESET_M(A);
    tl += ls;
    if (tl >= tend) break;
    { int n = tl + 2 * ls; if (n < tend) LOADSET_M(A, n); }
    COMPUTESET_M(B);
    tl += ls;
    if (tl >= tend) break;
    { int n = tl + 2 * ls; if (n < tend) LOADSET_M(B, n); }
    COMPUTESET_M(C);
    tl += ls;
  }
}

// -------- last-resort fallback (unsorted edge order, plain atomics) ----------
__global__ __launch_bounds__(256, 2) void cfconv_edge_atomic(
    const int* __restrict__ ei, const float* __restrict__ ew,
    const float* __restrict__ attr,
    const float* __restrict__ w1, const float* __restrict__ b1,
    const float* __restrict__ w2, const float* __restrict__ b2,
    const unsigned short* __restrict__ h1bT, float* __restrict__ agg) {
  __shared__ __align__(16) short sB2[16384];
  __shared__ __align__(16) short sX[4][2048];
  __shared__ float sb1[128], sb2[128];
  const int tid = threadIdx.x;
  if (tid < 128) { sb1[tid] = b1[tid]; sb2[tid] = b2[tid]; }
  for (int i = tid; i < 8192; i += 256) {
    int p = i & 3, l = (i >> 2) & 63, t = (i >> 8) & 7, s = i >> 11;
    int k = s * 32 + (l >> 4) * 8 + p * 2;
    int f = t * 16 + (l & 15);
    f32x2 v = *(const f32x2*)(w2 + f * 128 + k);
    ((unsigned*)sB2)[i] = cvt_pk(v.x, v.y);
  }
  __syncthreads();
  const int lane = tid & 63, wave = tid >> 6, lrow = lane & 15, lk = lane >> 4;
  s16x8 B1r[16];
  {
    unsigned* bp = (unsigned*)B1r;
#pragma unroll
    for (int s = 0; s < 2; ++s)
#pragma unroll
      for (int t = 0; t < 8; ++t) {
        const float* wrow = w1 + (t * 16 + lrow) * NG;
#pragma unroll
        for (int p = 0; p < 4; ++p) {
          int k = s * 32 + lk * 8 + p * 2;
          f32x2 v = {0.f, 0.f};
          if (k < NG) v = *(const f32x2*)(wrow + k);
          bp[(s * 8 + t) * 4 + p] = cvt_pk(v.x, v.y);
        }
      }
  }
  const s16x8* B2 = (const s16x8*)sB2;
  char* sXw = (char*)sX[wave];
  const int gw0 = blockIdx.x * 4 + wave;
  const int gstride = gridDim.x * 4;
  for (int wt = gw0; wt < NTILES; wt += gstride) {
    const int e0 = wt * 16;
    int dst[4], src[4];
    float cw[4];
#pragma unroll
    for (int r = 0; r < 4; ++r) {
      int e = e0 + lk * 4 + r;
      dst[r] = ei[e];
      src[r] = ei[NEDGES + e];
      cw[r] = 0.5f * (__cosf(ew[e] * PI_OVER_CUT) + 1.f);
    }
    s16x8 hv8[4];
#pragma unroll
    for (int r = 0; r < 4; ++r)
      hv8[r] = *(const s16x8*)(h1bT + (size_t)src[r] * 128 + lrow * 8);
    const float* ar = attr + (size_t)(e0 + lrow) * NG;
    s16x8 av0, av1;
    unsigned* a0 = (unsigned*)&av0;
    unsigned* a1 = (unsigned*)&av1;
#pragma unroll
    for (int jj = 0; jj < 4; ++jj) {
      f32x2 v = *(const f32x2*)(ar + lk * 8 + jj * 2);
      a0[jj] = cvt_pk(v.x, v.y);
    }
#pragma unroll
    for (int jj = 0; jj < 4; ++jj) {
      int k = 32 + lk * 8 + jj * 2;
      f32x2 v = {0.f, 0.f};
      if (k < NG) v = *(const f32x2*)(ar + k);
      a1[jj] = cvt_pk(v.x, v.y);
    }
    f32x4 acc[8] = {};
#pragma unroll
    for (int t = 0; t < 8; ++t) acc[t] = MFMA16(av0, B1r[t], acc[t]);
#pragma unroll
    for (int t = 0; t < 8; ++t) acc[t] = MFMA16(av1, B1r[8 + t], acc[t]);
#pragma unroll
    for (int t = 0; t < 8; ++t) {
      int f = t * 16 + lrow;
      float bb = sb1[f];
#pragma unroll
      for (int r = 0; r < 4; ++r) {
        int row = lk * 4 + r;
        float v = sp_shift(acc[t][r] + bb);
        int a = (row * 256 + f * 2) ^ ((row & 7) << 4);
        *(short*)(sXw + a) = f2bf(v);
      }
    }
    f32x4 acc2[8] = {};
#pragma unroll
    for (int s = 0; s < 4; ++s) {
      int ab = (lrow * 256 + s * 64 + lk * 16) ^ ((lrow & 7) << 4);
      s16x8 av = *(const s16x8*)(sXw + ab);
#pragma unroll
      for (int t = 0; t < 8; ++t)
        acc2[t] = MFMA16(av, B2[(s * 8 + t) * 64 + lane], acc2[t]);
    }
#pragma unroll
    for (int t = 0; t < 8; ++t) {
      int f = t * 16 + lrow;
      float bb = sb2[f];
#pragma unroll
      for (int r = 0; r < 4; ++r) {
        float Wv = sp_shift(acc2[t][r] + bb) * cw[r];
        atomicAdd(&agg[(size_t)dst[r] * 128 + f], Wv * bf2f((unsigned short)hv8[r][t]));
      }
    }
  }
}

extern "C" void kernel_launch(void* const* d_in, const int* in_sizes, int n_in,
                              void* d_out, int out_size, void* d_ws, size_t ws_size,
                              hipStream_t stream) {
  const float* h      = (const float*)d_in[0];
  const int*   ei     = (const int*)d_in[1];
  const float* ew     = (const float*)d_in[2];
  const float* attr   = (const float*)d_in[3];
  const float* lin1_w = (const float*)d_in[4];
  const float* nn_w1  = (const float*)d_in[5];
  const float* nn_b1  = (const float*)d_in[6];
  const float* nn_w2  = (const float*)d_in[7];
  const float* nn_b2  = (const float*)d_in[8];
  const float* lin2_w = (const float*)d_in[9];
  const float* lin2_b = (const float*)d_in[10];
  float* out = (float*)d_out;   // agg accumulator, then final output (in-place lin2)

  const int rbM = (NNODES + 63) / 64;
  const int EB  = (NEDGES + 255) / 256;

  // ws: cnt[SCAN_N] | bsum | meta(int4) | h1bT           (~26.1 MB)
  const size_t off_bs   = (size_t)SCAN_N * 4;
  const size_t off_meta = off_bs + 1024;
  const size_t off_h1b  = off_meta + (size_t)NEDGES * 16;
  const size_t need_main = off_h1b + (size_t)NNODES * 256;
  const size_t need_fb   = (size_t)NNODES * 256;   // h1bT only

  if (ws_size >= need_main) {
    int*  cnt  = (int*)d_ws;
    int*  bsum = (int*)((char*)d_ws + off_bs);
    int4* meta = (int4*)((char*)d_ws + off_meta);
    unsigned short* h1bT = (unsigned short*)((char*)d_ws + off_h1b);

    hipMemsetAsync(cnt, 0, (size_t)SCAN_N * 4, stream);
    k_hist<<<EB, 256, 0, stream>>>(ei, cnt);
    k_scanA<<<SCAN_BLK, 256, 0, stream>>>(cnt, bsum);
    k_scanB<<<1, 256, 0, stream>>>(bsum);
    k_scanC<<<SCAN_BLK, 256, 0, stream>>>(cnt, bsum);
    k_prepM<<<EB, 256, 0, stream>>>(ei, ew, cnt, meta);
    lin1_mfma<<<rbM, 256, 0, stream>>>(h, lin1_w, h1bT, out);   // zeroes agg=out
    cfconv_edge_m<<<512, 256, 0, stream>>>(meta, attr, nn_w1, nn_b1,
                                           nn_w2, nn_b2, h1bT, out);
    lin2_mfma<<<rbM, 256, 0, stream>>>(h1bT, out, lin2_w, lin2_b, out);  // in-place
  } else if (ws_size >= need_fb) {
    unsigned short* h1bT = (unsigned short*)d_ws;
    lin1_mfma<<<rbM, 256, 0, stream>>>(h, lin1_w, h1bT, out);   // zeroes agg=out
    cfconv_edge_atomic<<<512, 256, 0, stream>>>(ei, ew, attr, nn_w1, nn_b1,
                                                nn_w2, nn_b2, h1bT, out);
    lin2_mfma<<<rbM, 256, 0, stream>>>(h1bT, out, lin2_w, lin2_b, out);
  }
}

// Round 20
// 300.496 us; speedup vs baseline: 1.3988x; 1.3988x over previous
//
#include <hip/hip_runtime.h>

#define NNODES 50000
#define NEDGES 800000
#define NG 50
#define PI_OVER_CUT 0.31415926535897931f
#define LN2 0.69314718055994531f

static_assert(NEDGES % 16 == 0, "edge tiling assumes E % 16 == 0");
static_assert((NG & 1) == 0, "pair loads assume NG even");
#define NTILES (NEDGES / 16)
static_assert(NTILES % 8 == 0, "XCD partition assumes NTILES % 8 == 0");
#define SCAN_N 50176            // 196 * 256 >= NNODES
#define SCAN_BLK 196

typedef float f32x4 __attribute__((ext_vector_type(4)));
typedef float f32x2 __attribute__((ext_vector_type(2)));
typedef float f32x4u __attribute__((ext_vector_type(4), aligned(4)));
typedef short s16x8 __attribute__((ext_vector_type(8)));

// packed f32x2 -> bf16x2 (RNE), single instruction on gfx950
static __device__ __forceinline__ unsigned cvt_pk(float lo, float hi) {
  unsigned r;
  asm("v_cvt_pk_bf16_f32 %0, %1, %2" : "=v"(r) : "v"(lo), "v"(hi));
  return r;
}

static __device__ __forceinline__ short f2bf(float f) {
  union { float f; unsigned u; } v; v.f = f;
  return (short)((v.u + 0x7fffu + ((v.u >> 16) & 1u)) >> 16);  // RNE
}

static __device__ __forceinline__ float bf2f(unsigned short u) {
  union { unsigned u; float f; } v; v.u = (unsigned)u << 16;
  return v.f;
}

// softplus(x) - ln2, numerically stable (fallback-kernel use)
static __device__ __forceinline__ float sp_shift(float x) {
  return fmaxf(x, 0.f) + __logf(1.f + __expf(-fabsf(x))) - LN2;
}

// w such that softplus(x) = w * ln2. ~5 HW ops.
// Overflow-safe for x < ~80 (|acc| bounded ~55 here); large-negative -> 0 exactly.
static __device__ __forceinline__ float sp_w(float x) {
  return __log2f(1.f + __expf(x));
}

#define MFMA16(A, B, C) __builtin_amdgcn_mfma_f32_16x16x32_bf16((A), (B), (C), 0, 0, 0)

// h1bT layout: [node][lr<16][t<8] bf16 (element (lr,t) = h1[node][t*16+lr]).
// 256B per node. Edge-kernel gather of one lane's 8 values = one 16B load.

// ------- MFMA lin1: h1bT = bf16(X @ W^T) (transposed frag layout);
//         also zeroes this block's agg rows --------------------------------
__global__ __launch_bounds__(256) void lin1_mfma(const float* __restrict__ X,
                                                 const float* __restrict__ W,
                                                 unsigned short* __restrict__ Y2, // h1bT
                                                 float* __restrict__ aggz) {
  __shared__ __align__(16) short sB[16384];  // W frags: [s<4][t<8][lane][8]
  const int tid = threadIdx.x;
  if (aggz) {
    const size_t b0 = (size_t)blockIdx.x * 64 * 128;
    const size_t lim = (size_t)NNODES * 128;
    for (int i = tid; i < 64 * 32; i += 256) {
      size_t off = b0 + (size_t)i * 4;
      if (off < lim) *(f32x4*)(aggz + off) = f32x4{0.f, 0.f, 0.f, 0.f};
    }
  }
  for (int i = tid; i < 8192; i += 256) {    // i indexes bf16-pairs
    int p = i & 3, l = (i >> 2) & 63, t = (i >> 8) & 7, s = i >> 11;
    int k = s * 32 + (l >> 4) * 8 + p * 2;
    int f = t * 16 + (l & 15);
    f32x2 v = *(const f32x2*)(W + f * 128 + k);
    ((unsigned*)sB)[i] = cvt_pk(v.x, v.y);
  }
  __syncthreads();
  const int lane = tid & 63, wave = tid >> 6, lrow = lane & 15, lk = lane >> 4;
  const s16x8* B = (const s16x8*)sB;
  const int rowA = blockIdx.x * 64 + wave * 16 + lrow;
  s16x8 a[4];
#pragma unroll
  for (int s = 0; s < 4; ++s) {
    unsigned* ap = (unsigned*)&a[s];
    f32x4 v0 = {}, v1 = {};
    if (rowA < NNODES) {
      const float* xr = X + (size_t)rowA * 128 + s * 32 + lk * 8;
      v0 = *(const f32x4*)xr;
      v1 = *(const f32x4*)(xr + 4);
    }
    ap[0] = cvt_pk(v0.x, v0.y); ap[1] = cvt_pk(v0.z, v0.w);
    ap[2] = cvt_pk(v1.x, v1.y); ap[3] = cvt_pk(v1.z, v1.w);
  }
  f32x4 acc[8] = {};
#pragma unroll
  for (int s = 0; s < 4; ++s)
#pragma unroll
    for (int t = 0; t < 8; ++t)
      acc[t] = MFMA16(a[s], B[(s * 8 + t) * 64 + lane], acc[t]);
  const int rowD = blockIdx.x * 64 + wave * 16 + lk * 4;
#pragma unroll
  for (int r = 0; r < 4; ++r) {
    int node = rowD + r;
    if (node < NNODES) {
      uint4 q;
      q.x = cvt_pk(acc[0][r], acc[1][r]);
      q.y = cvt_pk(acc[2][r], acc[3][r]);
      q.z = cvt_pk(acc[4][r], acc[5][r]);
      q.w = cvt_pk(acc[6][r], acc[7][r]);
      *(uint4*)(Y2 + (size_t)node * 128 + lrow * 8) = q;
    }
  }
}

// ---------------- MFMA lin2: OUT = (bf2f(h1bT) + AG) @ W^T + b ---------------
// AG may alias OUT (in-place): each wave reads/writes only its own 16 rows.
__global__ __launch_bounds__(256) void lin2_mfma(const unsigned short* __restrict__ H1bT,
                                                 const float* AG,
                                                 const float* __restrict__ W,
                                                 const float* __restrict__ Bias,
                                                 float* OUT) {
  __shared__ __align__(16) short sB[16384];
  const int tid = threadIdx.x;
  for (int i = tid; i < 8192; i += 256) {
    int p = i & 3, l = (i >> 2) & 63, t = (i >> 8) & 7, s = i >> 11;
    int k = s * 32 + (l >> 4) * 8 + p * 2;
    int f = t * 16 + (l & 15);
    f32x2 v = *(const f32x2*)(W + f * 128 + k);
    ((unsigned*)sB)[i] = cvt_pk(v.x, v.y);
  }
  __syncthreads();
  const int lane = tid & 63, wave = tid >> 6, lrow = lane & 15, lk = lane >> 4;
  const s16x8* B = (const s16x8*)sB;
  const int rowA = blockIdx.x * 64 + wave * 16 + lrow;
  s16x8 a[4];
#pragma unroll
  for (int s = 0; s < 4; ++s) {
    unsigned* ap = (unsigned*)&a[s];
    float w[8] = {};
    if (rowA < NNODES) {
      const float* gr = AG + (size_t)rowA * 128 + s * 32 + lk * 8;
      f32x4 g0 = *(const f32x4*)gr;
      f32x4 g1 = *(const f32x4*)(gr + 4);
#pragma unroll
      for (int j = 0; j < 8; ++j) {
        int c = s * 32 + lk * 8 + j;   // original column
        float hv = bf2f(H1bT[(size_t)rowA * 128 + (c & 15) * 8 + (c >> 4)]);
        w[j] = hv + (j < 4 ? g0[j] : g1[j - 4]);
      }
    }
    ap[0] = cvt_pk(w[0], w[1]); ap[1] = cvt_pk(w[2], w[3]);
    ap[2] = cvt_pk(w[4], w[5]); ap[3] = cvt_pk(w[6], w[7]);
  }
  f32x4 acc[8] = {};
#pragma unroll
  for (int s = 0; s < 4; ++s)
#pragma unroll
    for (int t = 0; t < 8; ++t)
      acc[t] = MFMA16(a[s], B[(s * 8 + t) * 64 + lane], acc[t]);
  const int rowD = blockIdx.x * 64 + wave * 16 + lk * 4;
#pragma unroll
  for (int t = 0; t < 8; ++t) {
    float bb = Bias[t * 16 + lrow];
#pragma unroll
    for (int r = 0; r < 4; ++r)
      if (rowD + r < NNODES)
        OUT[(size_t)(rowD + r) * 128 + t * 16 + lrow] = acc[t][r] + bb;
  }
}

// ---------------- sort machinery ---------------------------------------------
__global__ void k_hist(const int* __restrict__ ei, int* __restrict__ cnt) {
  int e = blockIdx.x * 256 + threadIdx.x;
  if (e < NEDGES) atomicAdd(&cnt[ei[e]], 1);
}

__global__ __launch_bounds__(256) void k_scanA(int* __restrict__ cnt,
                                               int* __restrict__ bsum) {
  __shared__ int sh[256];
  const int t = threadIdx.x;
  const int i = blockIdx.x * 256 + t;
  int v = cnt[i];
  sh[t] = v;
  __syncthreads();
  for (int off = 1; off < 256; off <<= 1) {
    int u = (t >= off) ? sh[t - off] : 0;
    __syncthreads();
    sh[t] += u;
    __syncthreads();
  }
  cnt[i] = sh[t] - v;
  if (t == 255) bsum[blockIdx.x] = sh[255];
}

__global__ __launch_bounds__(256) void k_scanB(int* __restrict__ bsum) {
  __shared__ int sh[256];
  const int t = threadIdx.x;
  int v = (t < SCAN_BLK) ? bsum[t] : 0;
  sh[t] = v;
  __syncthreads();
  for (int off = 1; off < 256; off <<= 1) {
    int u = (t >= off) ? sh[t - off] : 0;
    __syncthreads();
    sh[t] += u;
    __syncthreads();
  }
  if (t < SCAN_BLK) bsum[t] = sh[t] - v;
}

__global__ __launch_bounds__(256) void k_scanC(int* __restrict__ cnt,
                                               const int* __restrict__ bsum) {
  int i = blockIdx.x * 256 + threadIdx.x;
  cnt[i] += bsum[blockIdx.x];
}

// ---- prepass: meta only (dst,src,cw,eid) scattered to sorted position -------
__global__ void k_prepM(const int* __restrict__ ei, const float* __restrict__ ew,
                        int* __restrict__ cursor, int4* __restrict__ meta) {
  int e = blockIdx.x * 256 + threadIdx.x;
  if (e >= NEDGES) return;
  int d = ei[e], s = ei[NEDGES + e];
  float c = 0.5f * (__cosf(ew[e] * PI_OVER_CUT) + 1.f);
  int pos = atomicAdd(&cursor[d], 1);
  meta[pos] = make_int4(d, s, __float_as_int(c), e);
}

// ---------------- K2: fused stage1+2, dst-sorted, meta-fed, 2-deep pipeline --
#define LOADSET_M(S, TL)                                                       \
  {                                                                            \
    const int base_ = (TL) * 16;                                               \
    const int4* mp_ = meta + base_ + lk * 4;                                   \
    int4 m0_ = mp_[0], m1_ = mp_[1], m2_ = mp_[2], m3_ = mp_[3];               \
    dst_##S[0] = m0_.x; dst_##S[1] = m1_.x; dst_##S[2] = m2_.x; dst_##S[3] = m3_.x; \
    src_##S[0] = m0_.y; src_##S[1] = m1_.y; src_##S[2] = m2_.y; src_##S[3] = m3_.y; \
    cw_##S[0] = __int_as_float(m0_.z); cw_##S[1] = __int_as_float(m1_.z);      \
    cw_##S[2] = __int_as_float(m2_.z); cw_##S[3] = __int_as_float(m3_.z);      \
    const int ser_ = meta[base_ + lrow].w;                                     \
    const float* ar_ = attr + (size_t)ser_ * NG;                               \
    unsigned* a0_ = (unsigned*)&av0_##S;                                       \
    unsigned* a1_ = (unsigned*)&av1_##S;                                       \
    if (ser_ < NEDGES - 1) {  /* fast: unmasked (pad lanes hit B=0) */         \
      f32x4u p0 = *(const f32x4u*)(ar_ + lk * 8);                              \
      f32x4u p1 = *(const f32x4u*)(ar_ + lk * 8 + 4);                          \
      f32x4u p2 = *(const f32x4u*)(ar_ + 32 + lk * 8);                         \
      f32x4u p3 = *(const f32x4u*)(ar_ + 32 + lk * 8 + 4);                     \
      a0_[0] = cvt_pk(p0.x, p0.y); a0_[1] = cvt_pk(p0.z, p0.w);                \
      a0_[2] = cvt_pk(p1.x, p1.y); a0_[3] = cvt_pk(p1.z, p1.w);                \
      a1_[0] = cvt_pk(p2.x, p2.y); a1_[1] = cvt_pk(p2.z, p2.w);                \
      a1_[2] = cvt_pk(p3.x, p3.y); a1_[3] = cvt_pk(p3.z, p3.w);                \
    } else {                                                                   \
      _Pragma("unroll") for (int jj = 0; jj < 4; ++jj) {                       \
        f32x2 v = *(const f32x2*)(ar_ + lk * 8 + jj * 2);                      \
        a0_[jj] = cvt_pk(v.x, v.y);                                            \
      }                                                                        \
      _Pragma("unroll") for (int jj = 0; jj < 4; ++jj) {                       \
        int k_ = 32 + lk * 8 + jj * 2;                                         \
        f32x2 v = {0.f, 0.f};                                                  \
        if (k_ < NG) v = *(const f32x2*)(ar_ + k_);                            \
        a1_[jj] = cvt_pk(v.x, v.y);                                            \
      }                                                                        \
    }                                                                          \
  }

#define COMPUTESET_M(S)                                                        \
  {                                                                            \
    s16x8 hv8[4];                                                              \
    _Pragma("unroll") for (int r = 0; r < 4; ++r)                              \
      hv8[r] = *(const s16x8*)(h1bT + (size_t)src_##S[r] * 128 + lrow * 8);    \
    f32x4 acc[8] = {};                                                         \
    _Pragma("unroll") for (int t = 0; t < 8; ++t)                              \
      acc[t] = MFMA16(av0_##S, B1r[t], acc[t]);                                \
    _Pragma("unroll") for (int t = 0; t < 8; ++t)                              \
      acc[t] = MFMA16(av1_##S, B1r[8 + t], acc[t]);                            \
    _Pragma("unroll") for (int t = 0; t < 8; ++t) {                            \
      int f = t * 16 + lrow;                                                   \
      float bb = sb1[f];                                                       \
      float w0 = sp_w(acc[t][0] + bb);                                         \
      float w1 = sp_w(acc[t][1] + bb);                                         \
      float w2 = sp_w(acc[t][2] + bb);                                         \
      float w3 = sp_w(acc[t][3] + bb);                                         \
      float v0 = __builtin_fmaf(w0, LN2, -LN2);                                \
      float v1 = __builtin_fmaf(w1, LN2, -LN2);                                \
      float v2 = __builtin_fmaf(w2, LN2, -LN2);                                \
      float v3 = __builtin_fmaf(w3, LN2, -LN2);                                \
      unsigned p01 = cvt_pk(v0, v1), p23 = cvt_pk(v2, v3);                     \
      const int row0_ = lk * 4;                                                \
      int a0 = ((row0_ + 0) * 256 + f * 2) ^ (((row0_ + 0) & 7) << 4);         \
      int a1 = ((row0_ + 1) * 256 + f * 2) ^ (((row0_ + 1) & 7) << 4);         \
      int a2 = ((row0_ + 2) * 256 + f * 2) ^ (((row0_ + 2) & 7) << 4);         \
      int a3 = ((row0_ + 3) * 256 + f * 2) ^ (((row0_ + 3) & 7) << 4);         \
      *(short*)(sXw + a0) = (short)p01;                                        \
      *(short*)(sXw + a1) = (short)(p01 >> 16);                                \
      *(short*)(sXw + a2) = (short)p23;                                        \
      *(short*)(sXw + a3) = (short)(p23 >> 16);                                \
    }                                                                          \
    f32x4 acc2[8] = {};                                                        \
    _Pragma("unroll") for (int s = 0; s < 4; ++s) {                            \
      int ab = (lrow * 256 + s * 64 + lk * 16) ^ ((lrow & 7) << 4);            \
      s16x8 av = *(const s16x8*)(sXw + ab);                                    \
      _Pragma("unroll") for (int t = 0; t < 8; ++t)                            \
        acc2[t] = MFMA16(av, B2[(s * 8 + t) * 64 + lane], acc2[t]);            \
    }                                                                          \
    const float lc0 = cw_##S[0] * LN2, lc1 = cw_##S[1] * LN2;                  \
    const float lc2 = cw_##S[2] * LN2, lc3 = cw_##S[3] * LN2;                  \
    const int d0 = dst_##S[0], d3 = dst_##S[3];                                \
    const bool b1f = dst_##S[1] != d0, b2f = dst_##S[2] != dst_##S[1],         \
               b3f = d3 != dst_##S[2];                                         \
    const bool allsame = !(b1f | b2f | b3f);                                   \
    const int next_head = __shfl(d0, (lane + 16) & 63);                        \
    const bool tor = (lk < 3) && (next_head == d3);                            \
    const int td0 = __shfl(d3, lrow);                                          \
    const int td1 = __shfl(d3, lrow + 16);                                     \
    const int td2 = __shfl(d3, lrow + 32);                                     \
    const bool m0 = (lk >= 1) && (td0 == d0);                                  \
    const bool m1 = (lk >= 2) && (td1 == d0);                                  \
    const bool m2 = (lk >= 3) && (td2 == d0);                                  \
    const bool emit_head = !(allsame && tor);                                  \
    const bool emit_tail = (!allsame) && !tor;                                 \
    const bool mid1 = b1f && b2f, mid2 = b2f && b3f,                           \
               mid12 = b1f && (!b2f) && b3f;                                   \
    _Pragma("unroll") for (int t = 0; t < 8; ++t) {                            \
      int f = t * 16 + lrow;                                                   \
      float bb = sb2[f];                                                       \
      float w0 = sp_w(acc2[t][0] + bb);                                        \
      float w1 = sp_w(acc2[t][1] + bb);                                        \
      float w2 = sp_w(acc2[t][2] + bb);                                        \
      float w3 = sp_w(acc2[t][3] + bb);                                        \
      float v0 = __builtin_fmaf(w0, lc0, -lc0) * bf2f((unsigned short)hv8[0][t]); \
      float v1 = __builtin_fmaf(w1, lc1, -lc1) * bf2f((unsigned short)hv8[1][t]); \
      float v2 = __builtin_fmaf(w2, lc2, -lc2) * bf2f((unsigned short)hv8[2][t]); \
      float v3 = __builtin_fmaf(w3, lc3, -lc3) * bf2f((unsigned short)hv8[3][t]); \
      float head_sum = v0 + (b1f ? 0.f : v1 + (b2f ? 0.f : v2 + (b3f ? 0.f : v3))); \
      float tail_sum = v3 + (b3f ? 0.f : v2 + (b2f ? 0.f : v1 + (b1f ? 0.f : v0))); \
      float ts0 = __shfl(tail_sum, lrow);                                      \
      float ts1 = __shfl(tail_sum, lrow + 16);                                 \
      float ts2 = __shfl(tail_sum, lrow + 32);                                 \
      float carry = (m0 ? ts0 : 0.f) + (m1 ? ts1 : 0.f) + (m2 ? ts2 : 0.f);    \
      if (emit_head) atomicAdd(&agg[(size_t)d0 * 128 + f], head_sum + carry);  \
      if (emit_tail) atomicAdd(&agg[(size_t)d3 * 128 + f], tail_sum);          \
      if (mid1) atomicAdd(&agg[(size_t)dst_##S[1] * 128 + f], v1);             \
      if (mid2) atomicAdd(&agg[(size_t)dst_##S[2] * 128 + f], v2);             \
      if (mid12) atomicAdd(&agg[(size_t)dst_##S[1] * 128 + f], v1 + v2);       \
    }                                                                          \
  }

// XCD-aware partition: blocks presumed round-robin over 8 XCDs (bid & 7).
// Give each XCD a CONTIGUOUS dst-sorted tile range so its agg atomics hit a
// ~3.2MB node window that fits the XCD-private 4MB L2.
__global__ __launch_bounds__(256, 2) void cfconv_edge_m(
    const int4* __restrict__ meta, const float* __restrict__ attr,
    const float* __restrict__ w1, const float* __restrict__ b1,
    const float* __restrict__ w2, const float* __restrict__ b2,
    const unsigned short* __restrict__ h1bT, float* __restrict__ agg) {
  __shared__ __align__(16) short sB2[16384];   // W2^T frags: [s<4][t<8][lane][8]
  __shared__ __align__(16) short sX[4][2048];  // per-wave X tile [16][128] bf16, swizzled
  __shared__ float sb1[128], sb2[128];
  const int tid = threadIdx.x;
  if (tid < 128) { sb1[tid] = b1[tid]; sb2[tid] = b2[tid]; }
  for (int i = tid; i < 8192; i += 256) {
    int p = i & 3, l = (i >> 2) & 63, t = (i >> 8) & 7, s = i >> 11;
    int k = s * 32 + (l >> 4) * 8 + p * 2;
    int f = t * 16 + (l & 15);
    f32x2 v = *(const f32x2*)(w2 + f * 128 + k);
    ((unsigned*)sB2)[i] = cvt_pk(v.x, v.y);
  }
  __syncthreads();
  const int lane = tid & 63;
  const int wave = tid >> 6;
  const int lrow = lane & 15;
  const int lk = lane >> 4;
  // B1 frags -> registers (16 frags x 4 VGPR), built once per wave
  s16x8 B1r[16];
  {
    unsigned* bp = (unsigned*)B1r;
#pragma unroll
    for (int s = 0; s < 2; ++s)
#pragma unroll
      for (int t = 0; t < 8; ++t) {
        const float* wrow = w1 + (t * 16 + lrow) * NG;
#pragma unroll
        for (int p = 0; p < 4; ++p) {
          int k = s * 32 + lk * 8 + p * 2;
          f32x2 v = {0.f, 0.f};
          if (k < NG) v = *(const f32x2*)(wrow + k);
          bp[(s * 8 + t) * 4 + p] = cvt_pk(v.x, v.y);
        }
      }
  }
  const s16x8* B2 = (const s16x8*)sB2;
  char* sXw = (char*)sX[wave];

  // XCD partition of tile space
  const int xcd  = blockIdx.x & 7;
  const int lb   = blockIdx.x >> 3;            // local block within XCD group
  const int tpx  = NTILES / 8;                 // tiles per XCD (6250)
  const int tend = (xcd + 1) * tpx;
  const int lstride = (gridDim.x >> 3) * 4;    // waves per XCD group
  const int gw0 = xcd * tpx + lb * 4 + wave;

  s16x8 av0_A, av1_A, av0_B, av1_B;
  int dst_A[4], src_A[4], dst_B[4], src_B[4];
  float cw_A[4], cw_B[4];

  int tl = gw0;
  if (tl < tend) LOADSET_M(A, tl);
  while (tl < tend) {
    int n1 = tl + lstride;
    if (n1 < tend) LOADSET_M(B, n1);
    COMPUTESET_M(A);
    tl = n1;
    if (tl >= tend) break;
    int n2 = tl + lstride;
    if (n2 < tend) LOADSET_M(A, n2);
    COMPUTESET_M(B);
    tl = n2;
  }
}

// -------- last-resort fallback (unsorted edge order, plain atomics) ----------
__global__ __launch_bounds__(256, 2) void cfconv_edge_atomic(
    const int* __restrict__ ei, const float* __restrict__ ew,
    const float* __restrict__ attr,
    const float* __restrict__ w1, const float* __restrict__ b1,
    const float* __restrict__ w2, const float* __restrict__ b2,
    const unsigned short* __restrict__ h1bT, float* __restrict__ agg) {
  __shared__ __align__(16) short sB2[16384];
  __shared__ __align__(16) short sX[4][2048];
  __shared__ float sb1[128], sb2[128];
  const int tid = threadIdx.x;
  if (tid < 128) { sb1[tid] = b1[tid]; sb2[tid] = b2[tid]; }
  for (int i = tid; i < 8192; i += 256) {
    int p = i & 3, l = (i >> 2) & 63, t = (i >> 8) & 7, s = i >> 11;
    int k = s * 32 + (l >> 4) * 8 + p * 2;
    int f = t * 16 + (l & 15);
    f32x2 v = *(const f32x2*)(w2 + f * 128 + k);
    ((unsigned*)sB2)[i] = cvt_pk(v.x, v.y);
  }
  __syncthreads();
  const int lane = tid & 63, wave = tid >> 6, lrow = lane & 15, lk = lane >> 4;
  s16x8 B1r[16];
  {
    unsigned* bp = (unsigned*)B1r;
#pragma unroll
    for (int s = 0; s < 2; ++s)
#pragma unroll
      for (int t = 0; t < 8; ++t) {
        const float* wrow = w1 + (t * 16 + lrow) * NG;
#pragma unroll
        for (int p = 0; p < 4; ++p) {
          int k = s * 32 + lk * 8 + p * 2;
          f32x2 v = {0.f, 0.f};
          if (k < NG) v = *(const f32x2*)(wrow + k);
          bp[(s * 8 + t) * 4 + p] = cvt_pk(v.x, v.y);
        }
      }
  }
  const s16x8* B2 = (const s16x8*)sB2;
  char* sXw = (char*)sX[wave];
  const int gw0 = blockIdx.x * 4 + wave;
  const int gstride = gridDim.x * 4;
  for (int wt = gw0; wt < NTILES; wt += gstride) {
    const int e0 = wt * 16;
    int dst[4], src[4];
    float cw[4];
#pragma unroll
    for (int r = 0; r < 4; ++r) {
      int e = e0 + lk * 4 + r;
      dst[r] = ei[e];
      src[r] = ei[NEDGES + e];
      cw[r] = 0.5f * (__cosf(ew[e] * PI_OVER_CUT) + 1.f);
    }
    s16x8 hv8[4];
#pragma unroll
    for (int r = 0; r < 4; ++r)
      hv8[r] = *(const s16x8*)(h1bT + (size_t)src[r] * 128 + lrow * 8);
    const float* ar = attr + (size_t)(e0 + lrow) * NG;
    s16x8 av0, av1;
    unsigned* a0 = (unsigned*)&av0;
    unsigned* a1 = (unsigned*)&av1;
#pragma unroll
    for (int jj = 0; jj < 4; ++jj) {
      f32x2 v = *(const f32x2*)(ar + lk * 8 + jj * 2);
      a0[jj] = cvt_pk(v.x, v.y);
    }
#pragma unroll
    for (int jj = 0; jj < 4; ++jj) {
      int k = 32 + lk * 8 + jj * 2;
      f32x2 v = {0.f, 0.f};
      if (k < NG) v = *(const f32x2*)(ar + k);
      a1[jj] = cvt_pk(v.x, v.y);
    }
    f32x4 acc[8] = {};
#pragma unroll
    for (int t = 0; t < 8; ++t) acc[t] = MFMA16(av0, B1r[t], acc[t]);
#pragma unroll
    for (int t = 0; t < 8; ++t) acc[t] = MFMA16(av1, B1r[8 + t], acc[t]);
#pragma unroll
    for (int t = 0; t < 8; ++t) {
      int f = t * 16 + lrow;
      float bb = sb1[f];
#pragma unroll
      for (int r = 0; r < 4; ++r) {
        int row = lk * 4 + r;
        float v = sp_shift(acc[t][r] + bb);
        int a = (row * 256 + f * 2) ^ ((row & 7) << 4);
        *(short*)(sXw + a) = f2bf(v);
      }
    }
    f32x4 acc2[8] = {};
#pragma unroll
    for (int s = 0; s < 4; ++s) {
      int ab = (lrow * 256 + s * 64 + lk * 16) ^ ((lrow & 7) << 4);
      s16x8 av = *(const s16x8*)(sXw + ab);
#pragma unroll
      for (int t = 0; t < 8; ++t)
        acc2[t] = MFMA16(av, B2[(s * 8 + t) * 64 + lane], acc2[t]);
    }
#pragma unroll
    for (int t = 0; t < 8; ++t) {
      int f = t * 16 + lrow;
      float bb = sb2[f];
#pragma unroll
      for (int r = 0; r < 4; ++r) {
        float Wv = sp_shift(acc2[t][r] + bb) * cw[r];
        atomicAdd(&agg[(size_t)dst[r] * 128 + f], Wv * bf2f((unsigned short)hv8[r][t]));
      }
    }
  }
}

extern "C" void kernel_launch(void* const* d_in, const int* in_sizes, int n_in,
                              void* d_out, int out_size, void* d_ws, size_t ws_size,
                              hipStream_t stream) {
  const float* h      = (const float*)d_in[0];
  const int*   ei     = (const int*)d_in[1];
  const float* ew     = (const float*)d_in[2];
  const float* attr   = (const float*)d_in[3];
  const float* lin1_w = (const float*)d_in[4];
  const float* nn_w1  = (const float*)d_in[5];
  const float* nn_b1  = (const float*)d_in[6];
  const float* nn_w2  = (const float*)d_in[7];
  const float* nn_b2  = (const float*)d_in[8];
  const float* lin2_w = (const float*)d_in[9];
  const float* lin2_b = (const float*)d_in[10];
  float* out = (float*)d_out;   // agg accumulator, then final output (in-place lin2)

  const int rbM = (NNODES + 63) / 64;
  const int EB  = (NEDGES + 255) / 256;

  // ws: cnt[SCAN_N] | bsum | meta(int4) | h1bT           (~26.1 MB)
  const size_t off_bs   = (size_t)SCAN_N * 4;
  const size_t off_meta = off_bs + 1024;
  const size_t off_h1b  = off_meta + (size_t)NEDGES * 16;
  const size_t need_main = off_h1b + (size_t)NNODES * 256;
  const size_t need_fb   = (size_t)NNODES * 256;   // h1bT only

  if (ws_size >= need_main) {
    int*  cnt  = (int*)d_ws;
    int*  bsum = (int*)((char*)d_ws + off_bs);
    int4* meta = (int4*)((char*)d_ws + off_meta);
    unsigned short* h1bT = (unsigned short*)((char*)d_ws + off_h1b);

    hipMemsetAsync(cnt, 0, (size_t)SCAN_N * 4, stream);
    k_hist<<<EB, 256, 0, stream>>>(ei, cnt);
    k_scanA<<<SCAN_BLK, 256, 0, stream>>>(cnt, bsum);
    k_scanB<<<1, 256, 0, stream>>>(bsum);
    k_scanC<<<SCAN_BLK, 256, 0, stream>>>(cnt, bsum);
    k_prepM<<<EB, 256, 0, stream>>>(ei, ew, cnt, meta);
    lin1_mfma<<<rbM, 256, 0, stream>>>(h, lin1_w, h1bT, out);   // zeroes agg=out
    cfconv_edge_m<<<512, 256, 0, stream>>>(meta, attr, nn_w1, nn_b1,
                                           nn_w2, nn_b2, h1bT, out);
    lin2_mfma<<<rbM, 256, 0, stream>>>(h1bT, out, lin2_w, lin2_b, out);  // in-place
  } else if (ws_size >= need_fb) {
    unsigned short* h1bT = (unsigned short*)d_ws;
    lin1_mfma<<<rbM, 256, 0, stream>>>(h, lin1_w, h1bT, out);   // zeroes agg=out
    cfconv_edge_atomic<<<512, 256, 0, stream>>>(ei, ew, attr, nn_w1, nn_b1,
                                                nn_w2, nn_b2, h1bT, out);
    lin2_mfma<<<rbM, 256, 0, stream>>>(h1bT, out, lin2_w, lin2_b, out);
  }
}

// Round 21
// 296.529 us; speedup vs baseline: 1.4175x; 1.0134x over previous
//
#include <hip/hip_runtime.h>

#define NNODES 50000
#define NEDGES 800000
#define NG 50
#define PI_OVER_CUT 0.31415926535897931f
#define LN2 0.69314718055994531f

static_assert(NEDGES % 16 == 0, "edge tiling assumes E % 16 == 0");
static_assert((NG & 1) == 0, "pair loads assume NG even");
#define NTILES (NEDGES / 16)
static_assert(NTILES % 8 == 0, "XCD partition assumes NTILES % 8 == 0");
#define SCAN_N 50176            // 196 * 256 >= NNODES
#define SCAN_BLK 196

typedef float f32x4 __attribute__((ext_vector_type(4)));
typedef float f32x2 __attribute__((ext_vector_type(2)));
typedef float f32x4u __attribute__((ext_vector_type(4), aligned(4)));
typedef short s16x8 __attribute__((ext_vector_type(8)));

// packed f32x2 -> bf16x2 (RNE), single instruction on gfx950
static __device__ __forceinline__ unsigned cvt_pk(float lo, float hi) {
  unsigned r;
  asm("v_cvt_pk_bf16_f32 %0, %1, %2" : "=v"(r) : "v"(lo), "v"(hi));
  return r;
}

static __device__ __forceinline__ short f2bf(float f) {
  union { float f; unsigned u; } v; v.f = f;
  return (short)((v.u + 0x7fffu + ((v.u >> 16) & 1u)) >> 16);  // RNE
}

static __device__ __forceinline__ float bf2f(unsigned short u) {
  union { unsigned u; float f; } v; v.u = (unsigned)u << 16;
  return v.f;
}

// softplus(x) - ln2, numerically stable (fallback-kernel use)
static __device__ __forceinline__ float sp_shift(float x) {
  return fmaxf(x, 0.f) + __logf(1.f + __expf(-fabsf(x))) - LN2;
}

// w such that softplus(x) = w * ln2. ~5 HW ops.
// Overflow-safe for x < ~80 (|acc| bounded ~55 here); large-negative -> 0 exactly.
static __device__ __forceinline__ float sp_w(float x) {
  return __log2f(1.f + __expf(x));
}

#define MFMA16(A, B, C) __builtin_amdgcn_mfma_f32_16x16x32_bf16((A), (B), (C), 0, 0, 0)

// h1bT layout: [node][lr<16][t<8] bf16 (element (lr,t) = h1[node][t*16+lr]).
// 256B per node. Edge-kernel gather of one lane's 8 values = one 16B load.

// ------- MFMA lin1: h1bT = bf16(X @ W^T) (transposed frag layout);
//         also zeroes this block's agg rows --------------------------------
__global__ __launch_bounds__(256) void lin1_mfma(const float* __restrict__ X,
                                                 const float* __restrict__ W,
                                                 unsigned short* __restrict__ Y2, // h1bT
                                                 float* __restrict__ aggz) {
  __shared__ __align__(16) short sB[16384];  // W frags: [s<4][t<8][lane][8]
  const int tid = threadIdx.x;
  if (aggz) {
    const size_t b0 = (size_t)blockIdx.x * 64 * 128;
    const size_t lim = (size_t)NNODES * 128;
    for (int i = tid; i < 64 * 32; i += 256) {
      size_t off = b0 + (size_t)i * 4;
      if (off < lim) *(f32x4*)(aggz + off) = f32x4{0.f, 0.f, 0.f, 0.f};
    }
  }
  for (int i = tid; i < 8192; i += 256) {    // i indexes bf16-pairs
    int p = i & 3, l = (i >> 2) & 63, t = (i >> 8) & 7, s = i >> 11;
    int k = s * 32 + (l >> 4) * 8 + p * 2;
    int f = t * 16 + (l & 15);
    f32x2 v = *(const f32x2*)(W + f * 128 + k);
    ((unsigned*)sB)[i] = cvt_pk(v.x, v.y);
  }
  __syncthreads();
  const int lane = tid & 63, wave = tid >> 6, lrow = lane & 15, lk = lane >> 4;
  const s16x8* B = (const s16x8*)sB;
  const int rowA = blockIdx.x * 64 + wave * 16 + lrow;
  s16x8 a[4];
#pragma unroll
  for (int s = 0; s < 4; ++s) {
    unsigned* ap = (unsigned*)&a[s];
    f32x4 v0 = {}, v1 = {};
    if (rowA < NNODES) {
      const float* xr = X + (size_t)rowA * 128 + s * 32 + lk * 8;
      v0 = *(const f32x4*)xr;
      v1 = *(const f32x4*)(xr + 4);
    }
    ap[0] = cvt_pk(v0.x, v0.y); ap[1] = cvt_pk(v0.z, v0.w);
    ap[2] = cvt_pk(v1.x, v1.y); ap[3] = cvt_pk(v1.z, v1.w);
  }
  f32x4 acc[8] = {};
#pragma unroll
  for (int s = 0; s < 4; ++s)
#pragma unroll
    for (int t = 0; t < 8; ++t)
      acc[t] = MFMA16(a[s], B[(s * 8 + t) * 64 + lane], acc[t]);
  const int rowD = blockIdx.x * 64 + wave * 16 + lk * 4;
#pragma unroll
  for (int r = 0; r < 4; ++r) {
    int node = rowD + r;
    if (node < NNODES) {
      uint4 q;
      q.x = cvt_pk(acc[0][r], acc[1][r]);
      q.y = cvt_pk(acc[2][r], acc[3][r]);
      q.z = cvt_pk(acc[4][r], acc[5][r]);
      q.w = cvt_pk(acc[6][r], acc[7][r]);
      *(uint4*)(Y2 + (size_t)node * 128 + lrow * 8) = q;
    }
  }
}

// ---------------- MFMA lin2: OUT = (bf2f(h1bT) + AG) @ W^T + b ---------------
// AG may alias OUT (in-place): each wave reads/writes only its own 16 rows.
__global__ __launch_bounds__(256) void lin2_mfma(const unsigned short* __restrict__ H1bT,
                                                 const float* AG,
                                                 const float* __restrict__ W,
                                                 const float* __restrict__ Bias,
                                                 float* OUT) {
  __shared__ __align__(16) short sB[16384];
  const int tid = threadIdx.x;
  for (int i = tid; i < 8192; i += 256) {
    int p = i & 3, l = (i >> 2) & 63, t = (i >> 8) & 7, s = i >> 11;
    int k = s * 32 + (l >> 4) * 8 + p * 2;
    int f = t * 16 + (l & 15);
    f32x2 v = *(const f32x2*)(W + f * 128 + k);
    ((unsigned*)sB)[i] = cvt_pk(v.x, v.y);
  }
  __syncthreads();
  const int lane = tid & 63, wave = tid >> 6, lrow = lane & 15, lk = lane >> 4;
  const s16x8* B = (const s16x8*)sB;
  const int rowA = blockIdx.x * 64 + wave * 16 + lrow;
  s16x8 a[4];
#pragma unroll
  for (int s = 0; s < 4; ++s) {
    unsigned* ap = (unsigned*)&a[s];
    float w[8] = {};
    if (rowA < NNODES) {
      const float* gr = AG + (size_t)rowA * 128 + s * 32 + lk * 8;
      f32x4 g0 = *(const f32x4*)gr;
      f32x4 g1 = *(const f32x4*)(gr + 4);
#pragma unroll
      for (int j = 0; j < 8; ++j) {
        int c = s * 32 + lk * 8 + j;   // original column
        float hv = bf2f(H1bT[(size_t)rowA * 128 + (c & 15) * 8 + (c >> 4)]);
        w[j] = hv + (j < 4 ? g0[j] : g1[j - 4]);
      }
    }
    ap[0] = cvt_pk(w[0], w[1]); ap[1] = cvt_pk(w[2], w[3]);
    ap[2] = cvt_pk(w[4], w[5]); ap[3] = cvt_pk(w[6], w[7]);
  }
  f32x4 acc[8] = {};
#pragma unroll
  for (int s = 0; s < 4; ++s)
#pragma unroll
    for (int t = 0; t < 8; ++t)
      acc[t] = MFMA16(a[s], B[(s * 8 + t) * 64 + lane], acc[t]);
  const int rowD = blockIdx.x * 64 + wave * 16 + lk * 4;
#pragma unroll
  for (int t = 0; t < 8; ++t) {
    float bb = Bias[t * 16 + lrow];
#pragma unroll
    for (int r = 0; r < 4; ++r)
      if (rowD + r < NNODES)
        OUT[(size_t)(rowD + r) * 128 + t * 16 + lrow] = acc[t][r] + bb;
  }
}

// ---------------- sort machinery ---------------------------------------------
__global__ void k_hist(const int* __restrict__ ei, int* __restrict__ cnt) {
  int e = blockIdx.x * 256 + threadIdx.x;
  if (e < NEDGES) atomicAdd(&cnt[ei[e]], 1);
}

__global__ __launch_bounds__(256) void k_scanA(int* __restrict__ cnt,
                                               int* __restrict__ bsum) {
  __shared__ int sh[256];
  const int t = threadIdx.x;
  const int i = blockIdx.x * 256 + t;
  int v = cnt[i];
  sh[t] = v;
  __syncthreads();
  for (int off = 1; off < 256; off <<= 1) {
    int u = (t >= off) ? sh[t - off] : 0;
    __syncthreads();
    sh[t] += u;
    __syncthreads();
  }
  cnt[i] = sh[t] - v;
  if (t == 255) bsum[blockIdx.x] = sh[255];
}

__global__ __launch_bounds__(256) void k_scanB(int* __restrict__ bsum) {
  __shared__ int sh[256];
  const int t = threadIdx.x;
  int v = (t < SCAN_BLK) ? bsum[t] : 0;
  sh[t] = v;
  __syncthreads();
  for (int off = 1; off < 256; off <<= 1) {
    int u = (t >= off) ? sh[t - off] : 0;
    __syncthreads();
    sh[t] += u;
    __syncthreads();
  }
  if (t < SCAN_BLK) bsum[t] = sh[t] - v;
}

__global__ __launch_bounds__(256) void k_scanC(int* __restrict__ cnt,
                                               const int* __restrict__ bsum) {
  int i = blockIdx.x * 256 + threadIdx.x;
  cnt[i] += bsum[blockIdx.x];
}

// ---- prepass: meta only (dst,src,cw,eid) scattered to sorted position -------
__global__ void k_prepM(const int* __restrict__ ei, const float* __restrict__ ew,
                        int* __restrict__ cursor, int4* __restrict__ meta) {
  int e = blockIdx.x * 256 + threadIdx.x;
  if (e >= NEDGES) return;
  int d = ei[e], s = ei[NEDGES + e];
  float c = 0.5f * (__cosf(ew[e] * PI_OVER_CUT) + 1.f);
  int pos = atomicAdd(&cursor[d], 1);
  meta[pos] = make_int4(d, s, __float_as_int(c), e);
}

// ---------------- K2: fused stage1+2, dst-sorted, meta-fed, 2-deep pipeline --
#define LOADSET_M(S, TL)                                                       \
  {                                                                            \
    const int base_ = (TL) * 16;                                               \
    const int4* mp_ = meta + base_ + lk * 4;                                   \
    int4 m0_ = mp_[0], m1_ = mp_[1], m2_ = mp_[2], m3_ = mp_[3];               \
    dst_##S[0] = m0_.x; dst_##S[1] = m1_.x; dst_##S[2] = m2_.x; dst_##S[3] = m3_.x; \
    src_##S[0] = m0_.y; src_##S[1] = m1_.y; src_##S[2] = m2_.y; src_##S[3] = m3_.y; \
    cw_##S[0] = __int_as_float(m0_.z); cw_##S[1] = __int_as_float(m1_.z);      \
    cw_##S[2] = __int_as_float(m2_.z); cw_##S[3] = __int_as_float(m3_.z);      \
    const int ser_ = meta[base_ + lrow].w;                                     \
    const float* ar_ = attr + (size_t)ser_ * NG;                               \
    unsigned* a0_ = (unsigned*)&av0_##S;                                       \
    unsigned* a1_ = (unsigned*)&av1_##S;                                       \
    if (ser_ < NEDGES - 1) {  /* fast: unmasked (pad lanes hit B=0) */         \
      f32x4u p0 = *(const f32x4u*)(ar_ + lk * 8);                              \
      f32x4u p1 = *(const f32x4u*)(ar_ + lk * 8 + 4);                          \
      f32x4u p2 = *(const f32x4u*)(ar_ + 32 + lk * 8);                         \
      f32x4u p3 = *(const f32x4u*)(ar_ + 32 + lk * 8 + 4);                     \
      a0_[0] = cvt_pk(p0.x, p0.y); a0_[1] = cvt_pk(p0.z, p0.w);                \
      a0_[2] = cvt_pk(p1.x, p1.y); a0_[3] = cvt_pk(p1.z, p1.w);                \
      a1_[0] = cvt_pk(p2.x, p2.y); a1_[1] = cvt_pk(p2.z, p2.w);                \
      a1_[2] = cvt_pk(p3.x, p3.y); a1_[3] = cvt_pk(p3.z, p3.w);                \
    } else {                                                                   \
      _Pragma("unroll") for (int jj = 0; jj < 4; ++jj) {                       \
        f32x2 v = *(const f32x2*)(ar_ + lk * 8 + jj * 2);                      \
        a0_[jj] = cvt_pk(v.x, v.y);                                            \
      }                                                                        \
      _Pragma("unroll") for (int jj = 0; jj < 4; ++jj) {                       \
        int k_ = 32 + lk * 8 + jj * 2;                                         \
        f32x2 v = {0.f, 0.f};                                                  \
        if (k_ < NG) v = *(const f32x2*)(ar_ + k_);                            \
        a1_[jj] = cvt_pk(v.x, v.y);                                            \
      }                                                                        \
    }                                                                          \
  }

#define COMPUTESET_M(S)                                                        \
  {                                                                            \
    s16x8 hv8[4];                                                              \
    _Pragma("unroll") for (int r = 0; r < 4; ++r)                              \
      hv8[r] = *(const s16x8*)(h1bT + (size_t)src_##S[r] * 128 + lrow * 8);    \
    f32x4 acc[8] = {};                                                         \
    __builtin_amdgcn_s_setprio(1);                                             \
    _Pragma("unroll") for (int t = 0; t < 8; ++t)                              \
      acc[t] = MFMA16(av0_##S, B1r[t], acc[t]);                                \
    _Pragma("unroll") for (int t = 0; t < 8; ++t)                              \
      acc[t] = MFMA16(av1_##S, B1r[8 + t], acc[t]);                            \
    __builtin_amdgcn_s_setprio(0);                                             \
    _Pragma("unroll") for (int t = 0; t < 8; ++t) {                            \
      int f = t * 16 + lrow;                                                   \
      float bb = sb1[f];                                                       \
      float w0 = sp_w(acc[t][0] + bb);                                         \
      float w1 = sp_w(acc[t][1] + bb);                                         \
      float w2 = sp_w(acc[t][2] + bb);                                         \
      float w3 = sp_w(acc[t][3] + bb);                                         \
      float v0 = __builtin_fmaf(w0, LN2, -LN2);                                \
      float v1 = __builtin_fmaf(w1, LN2, -LN2);                                \
      float v2 = __builtin_fmaf(w2, LN2, -LN2);                                \
      float v3 = __builtin_fmaf(w3, LN2, -LN2);                                \
      unsigned p01 = cvt_pk(v0, v1), p23 = cvt_pk(v2, v3);                     \
      const int row0_ = lk * 4;                                                \
      int a0 = ((row0_ + 0) * 256 + f * 2) ^ (((row0_ + 0) & 7) << 4);         \
      int a1 = ((row0_ + 1) * 256 + f * 2) ^ (((row0_ + 1) & 7) << 4);         \
      int a2 = ((row0_ + 2) * 256 + f * 2) ^ (((row0_ + 2) & 7) << 4);         \
      int a3 = ((row0_ + 3) * 256 + f * 2) ^ (((row0_ + 3) & 7) << 4);         \
      *(short*)(sXw + a0) = (short)p01;                                        \
      *(short*)(sXw + a1) = (short)(p01 >> 16);                                \
      *(short*)(sXw + a2) = (short)p23;                                        \
      *(short*)(sXw + a3) = (short)(p23 >> 16);                                \
    }                                                                          \
    f32x4 acc2[8] = {};                                                        \
    __builtin_amdgcn_s_setprio(1);                                             \
    _Pragma("unroll") for (int s = 0; s < 4; ++s) {                            \
      int ab = (lrow * 256 + s * 64 + lk * 16) ^ ((lrow & 7) << 4);            \
      s16x8 av = *(const s16x8*)(sXw + ab);                                    \
      _Pragma("unroll") for (int t = 0; t < 8; ++t)                            \
        acc2[t] = MFMA16(av, B2[(s * 8 + t) * 64 + lane], acc2[t]);            \
    }                                                                          \
    __builtin_amdgcn_s_setprio(0);                                             \
    const float lc0 = cw_##S[0] * LN2, lc1 = cw_##S[1] * LN2;                  \
    const float lc2 = cw_##S[2] * LN2, lc3 = cw_##S[3] * LN2;                  \
    const int d0 = dst_##S[0], d3 = dst_##S[3];                                \
    const bool b1f = dst_##S[1] != d0, b2f = dst_##S[2] != dst_##S[1],         \
               b3f = d3 != dst_##S[2];                                         \
    const bool allsame = !(b1f | b2f | b3f);                                   \
    const int next_head = __shfl(d0, (lane + 16) & 63);                        \
    const bool tor = (lk < 3) && (next_head == d3);                            \
    const int td0 = __shfl(d3, lrow);                                          \
    const int td1 = __shfl(d3, lrow + 16);                                     \
    const int td2 = __shfl(d3, lrow + 32);                                     \
    const bool m0 = (lk >= 1) && (td0 == d0);                                  \
    const bool m1 = (lk >= 2) && (td1 == d0);                                  \
    const bool m2 = (lk >= 3) && (td2 == d0);                                  \
    const bool emit_head = !(allsame && tor);                                  \
    const bool emit_tail = (!allsame) && !tor;                                 \
    const bool mid1 = b1f && b2f, mid2 = b2f && b3f,                           \
               mid12 = b1f && (!b2f) && b3f;                                   \
    _Pragma("unroll") for (int t = 0; t < 8; ++t) {                            \
      int f = t * 16 + lrow;                                                   \
      float bb = sb2[f];                                                       \
      float w0 = sp_w(acc2[t][0] + bb);                                        \
      float w1 = sp_w(acc2[t][1] + bb);                                        \
      float w2 = sp_w(acc2[t][2] + bb);                                        \
      float w3 = sp_w(acc2[t][3] + bb);                                        \
      float v0 = __builtin_fmaf(w0, lc0, -lc0) * bf2f((unsigned short)hv8[0][t]); \
      float v1 = __builtin_fmaf(w1, lc1, -lc1) * bf2f((unsigned short)hv8[1][t]); \
      float v2 = __builtin_fmaf(w2, lc2, -lc2) * bf2f((unsigned short)hv8[2][t]); \
      float v3 = __builtin_fmaf(w3, lc3, -lc3) * bf2f((unsigned short)hv8[3][t]); \
      float head_sum = v0 + (b1f ? 0.f : v1 + (b2f ? 0.f : v2 + (b3f ? 0.f : v3))); \
      float tail_sum = v3 + (b3f ? 0.f : v2 + (b2f ? 0.f : v1 + (b1f ? 0.f : v0))); \
      float ts0 = __shfl(tail_sum, lrow);                                      \
      float ts1 = __shfl(tail_sum, lrow + 16);                                 \
      float ts2 = __shfl(tail_sum, lrow + 32);                                 \
      float carry = (m0 ? ts0 : 0.f) + (m1 ? ts1 : 0.f) + (m2 ? ts2 : 0.f);    \
      if (emit_head) atomicAdd(&agg[(size_t)d0 * 128 + f], head_sum + carry);  \
      if (emit_tail) atomicAdd(&agg[(size_t)d3 * 128 + f], tail_sum);          \
      if (mid1) atomicAdd(&agg[(size_t)dst_##S[1] * 128 + f], v1);             \
      if (mid2) atomicAdd(&agg[(size_t)dst_##S[2] * 128 + f], v2);             \
      if (mid12) atomicAdd(&agg[(size_t)dst_##S[1] * 128 + f], v1 + v2);       \
    }                                                                          \
  }

// XCD-aware partition: blocks presumed round-robin over 8 XCDs (bid & 7).
// Give each XCD a CONTIGUOUS dst-sorted tile range so its agg atomics hit a
// ~3.2MB node window that fits the XCD-private 4MB L2.
__global__ __launch_bounds__(256, 2) void cfconv_edge_m(
    const int4* __restrict__ meta, const float* __restrict__ attr,
    const float* __restrict__ w1, const float* __restrict__ b1,
    const float* __restrict__ w2, const float* __restrict__ b2,
    const unsigned short* __restrict__ h1bT, float* __restrict__ agg) {
  __shared__ __align__(16) short sB2[16384];   // W2^T frags: [s<4][t<8][lane][8]
  __shared__ __align__(16) short sX[4][2048];  // per-wave X tile [16][128] bf16, swizzled
  __shared__ float sb1[128], sb2[128];
  const int tid = threadIdx.x;
  if (tid < 128) { sb1[tid] = b1[tid]; sb2[tid] = b2[tid]; }
  for (int i = tid; i < 8192; i += 256) {
    int p = i & 3, l = (i >> 2) & 63, t = (i >> 8) & 7, s = i >> 11;
    int k = s * 32 + (l >> 4) * 8 + p * 2;
    int f = t * 16 + (l & 15);
    f32x2 v = *(const f32x2*)(w2 + f * 128 + k);
    ((unsigned*)sB2)[i] = cvt_pk(v.x, v.y);
  }
  __syncthreads();
  const int lane = tid & 63;
  const int wave = tid >> 6;
  const int lrow = lane & 15;
  const int lk = lane >> 4;
  // B1 frags -> registers (16 frags x 4 VGPR), built once per wave
  s16x8 B1r[16];
  {
    unsigned* bp = (unsigned*)B1r;
#pragma unroll
    for (int s = 0; s < 2; ++s)
#pragma unroll
      for (int t = 0; t < 8; ++t) {
        const float* wrow = w1 + (t * 16 + lrow) * NG;
#pragma unroll
        for (int p = 0; p < 4; ++p) {
          int k = s * 32 + lk * 8 + p * 2;
          f32x2 v = {0.f, 0.f};
          if (k < NG) v = *(const f32x2*)(wrow + k);
          bp[(s * 8 + t) * 4 + p] = cvt_pk(v.x, v.y);
        }
      }
  }
  const s16x8* B2 = (const s16x8*)sB2;
  char* sXw = (char*)sX[wave];

  // XCD partition of tile space
  const int xcd  = blockIdx.x & 7;
  const int lb   = blockIdx.x >> 3;            // local block within XCD group
  const int tpx  = NTILES / 8;                 // tiles per XCD (6250)
  const int tend = (xcd + 1) * tpx;
  const int lstride = (gridDim.x >> 3) * 4;    // waves per XCD group
  const int gw0 = xcd * tpx + lb * 4 + wave;

  s16x8 av0_A, av1_A, av0_B, av1_B;
  int dst_A[4], src_A[4], dst_B[4], src_B[4];
  float cw_A[4], cw_B[4];

  int tl = gw0;
  if (tl < tend) LOADSET_M(A, tl);
  while (tl < tend) {
    int n1 = tl + lstride;
    if (n1 < tend) LOADSET_M(B, n1);
    COMPUTESET_M(A);
    tl = n1;
    if (tl >= tend) break;
    int n2 = tl + lstride;
    if (n2 < tend) LOADSET_M(A, n2);
    COMPUTESET_M(B);
    tl = n2;
  }
}

// -------- last-resort fallback (unsorted edge order, plain atomics) ----------
__global__ __launch_bounds__(256, 2) void cfconv_edge_atomic(
    const int* __restrict__ ei, const float* __restrict__ ew,
    const float* __restrict__ attr,
    const float* __restrict__ w1, const float* __restrict__ b1,
    const float* __restrict__ w2, const float* __restrict__ b2,
    const unsigned short* __restrict__ h1bT, float* __restrict__ agg) {
  __shared__ __align__(16) short sB2[16384];
  __shared__ __align__(16) short sX[4][2048];
  __shared__ float sb1[128], sb2[128];
  const int tid = threadIdx.x;
  if (tid < 128) { sb1[tid] = b1[tid]; sb2[tid] = b2[tid]; }
  for (int i = tid; i < 8192; i += 256) {
    int p = i & 3, l = (i >> 2) & 63, t = (i >> 8) & 7, s = i >> 11;
    int k = s * 32 + (l >> 4) * 8 + p * 2;
    int f = t * 16 + (l & 15);
    f32x2 v = *(const f32x2*)(w2 + f * 128 + k);
    ((unsigned*)sB2)[i] = cvt_pk(v.x, v.y);
  }
  __syncthreads();
  const int lane = tid & 63, wave = tid >> 6, lrow = lane & 15, lk = lane >> 4;
  s16x8 B1r[16];
  {
    unsigned* bp = (unsigned*)B1r;
#pragma unroll
    for (int s = 0; s < 2; ++s)
#pragma unroll
      for (int t = 0; t < 8; ++t) {
        const float* wrow = w1 + (t * 16 + lrow) * NG;
#pragma unroll
        for (int p = 0; p < 4; ++p) {
          int k = s * 32 + lk * 8 + p * 2;
          f32x2 v = {0.f, 0.f};
          if (k < NG) v = *(const f32x2*)(wrow + k);
          bp[(s * 8 + t) * 4 + p] = cvt_pk(v.x, v.y);
        }
      }
  }
  const s16x8* B2 = (const s16x8*)sB2;
  char* sXw = (char*)sX[wave];
  const int gw0 = blockIdx.x * 4 + wave;
  const int gstride = gridDim.x * 4;
  for (int wt = gw0; wt < NTILES; wt += gstride) {
    const int e0 = wt * 16;
    int dst[4], src[4];
    float cw[4];
#pragma unroll
    for (int r = 0; r < 4; ++r) {
      int e = e0 + lk * 4 + r;
      dst[r] = ei[e];
      src[r] = ei[NEDGES + e];
      cw[r] = 0.5f * (__cosf(ew[e] * PI_OVER_CUT) + 1.f);
    }
    s16x8 hv8[4];
#pragma unroll
    for (int r = 0; r < 4; ++r)
      hv8[r] = *(const s16x8*)(h1bT + (size_t)src[r] * 128 + lrow * 8);
    const float* ar = attr + (size_t)(e0 + lrow) * NG;
    s16x8 av0, av1;
    unsigned* a0 = (unsigned*)&av0;
    unsigned* a1 = (unsigned*)&av1;
#pragma unroll
    for (int jj = 0; jj < 4; ++jj) {
      f32x2 v = *(const f32x2*)(ar + lk * 8 + jj * 2);
      a0[jj] = cvt_pk(v.x, v.y);
    }
#pragma unroll
    for (int jj = 0; jj < 4; ++jj) {
      int k = 32 + lk * 8 + jj * 2;
      f32x2 v = {0.f, 0.f};
      if (k < NG) v = *(const f32x2*)(ar + k);
      a1[jj] = cvt_pk(v.x, v.y);
    }
    f32x4 acc[8] = {};
#pragma unroll
    for (int t = 0; t < 8; ++t) acc[t] = MFMA16(av0, B1r[t], acc[t]);
#pragma unroll
    for (int t = 0; t < 8; ++t) acc[t] = MFMA16(av1, B1r[8 + t], acc[t]);
#pragma unroll
    for (int t = 0; t < 8; ++t) {
      int f = t * 16 + lrow;
      float bb = sb1[f];
#pragma unroll
      for (int r = 0; r < 4; ++r) {
        int row = lk * 4 + r;
        float v = sp_shift(acc[t][r] + bb);
        int a = (row * 256 + f * 2) ^ ((row & 7) << 4);
        *(short*)(sXw + a) = f2bf(v);
      }
    }
    f32x4 acc2[8] = {};
#pragma unroll
    for (int s = 0; s < 4; ++s) {
      int ab = (lrow * 256 + s * 64 + lk * 16) ^ ((lrow & 7) << 4);
      s16x8 av = *(const s16x8*)(sXw + ab);
#pragma unroll
      for (int t = 0; t < 8; ++t)
        acc2[t] = MFMA16(av, B2[(s * 8 + t) * 64 + lane], acc2[t]);
    }
#pragma unroll
    for (int t = 0; t < 8; ++t) {
      int f = t * 16 + lrow;
      float bb = sb2[f];
#pragma unroll
      for (int r = 0; r < 4; ++r) {
        float Wv = sp_shift(acc2[t][r] + bb) * cw[r];
        atomicAdd(&agg[(size_t)dst[r] * 128 + f], Wv * bf2f((unsigned short)hv8[r][t]));
      }
    }
  }
}

extern "C" void kernel_launch(void* const* d_in, const int* in_sizes, int n_in,
                              void* d_out, int out_size, void* d_ws, size_t ws_size,
                              hipStream_t stream) {
  const float* h      = (const float*)d_in[0];
  const int*   ei     = (const int*)d_in[1];
  const float* ew     = (const float*)d_in[2];
  const float* attr   = (const float*)d_in[3];
  const float* lin1_w = (const float*)d_in[4];
  const float* nn_w1  = (const float*)d_in[5];
  const float* nn_b1  = (const float*)d_in[6];
  const float* nn_w2  = (const float*)d_in[7];
  const float* nn_b2  = (const float*)d_in[8];
  const float* lin2_w = (const float*)d_in[9];
  const float* lin2_b = (const float*)d_in[10];
  float* out = (float*)d_out;   // agg accumulator, then final output (in-place lin2)

  const int rbM = (NNODES + 63) / 64;
  const int EB  = (NEDGES + 255) / 256;

  // ws: cnt[SCAN_N] | bsum | meta(int4) | h1bT           (~26.1 MB)
  const size_t off_bs   = (size_t)SCAN_N * 4;
  const size_t off_meta = off_bs + 1024;
  const size_t off_h1b  = off_meta + (size_t)NEDGES * 16;
  const size_t need_main = off_h1b + (size_t)NNODES * 256;
  const size_t need_fb   = (size_t)NNODES * 256;   // h1bT only

  if (ws_size >= need_main) {
    int*  cnt  = (int*)d_ws;
    int*  bsum = (int*)((char*)d_ws + off_bs);
    int4* meta = (int4*)((char*)d_ws + off_meta);
    unsigned short* h1bT = (unsigned short*)((char*)d_ws + off_h1b);

    hipMemsetAsync(cnt, 0, (size_t)SCAN_N * 4, stream);
    k_hist<<<EB, 256, 0, stream>>>(ei, cnt);
    k_scanA<<<SCAN_BLK, 256, 0, stream>>>(cnt, bsum);
    k_scanB<<<1, 256, 0, stream>>>(bsum);
    k_scanC<<<SCAN_BLK, 256, 0, stream>>>(cnt, bsum);
    k_prepM<<<EB, 256, 0, stream>>>(ei, ew, cnt, meta);
    lin1_mfma<<<rbM, 256, 0, stream>>>(h, lin1_w, h1bT, out);   // zeroes agg=out
    cfconv_edge_m<<<512, 256, 0, stream>>>(meta, attr, nn_w1, nn_b1,
                                           nn_w2, nn_b2, h1bT, out);
    lin2_mfma<<<rbM, 256, 0, stream>>>(h1bT, out, lin2_w, lin2_b, out);  // in-place
  } else if (ws_size >= need_fb) {
    unsigned short* h1bT = (unsigned short*)d_ws;
    lin1_mfma<<<rbM, 256, 0, stream>>>(h, lin1_w, h1bT, out);   // zeroes agg=out
    cfconv_edge_atomic<<<512, 256, 0, stream>>>(ei, ew, attr, nn_w1, nn_b1,
                                                nn_w2, nn_b2, h1bT, out);
    lin2_mfma<<<rbM, 256, 0, stream>>>(h1bT, out, lin2_w, lin2_b, out);
  }
}